// Round 3
// baseline (1618.012 us; speedup 1.0000x reference)
//
#include <hip/hip_runtime.h>

#define DI __device__ __forceinline__

typedef _Float16 f16_t;
typedef _Float16 f16x8 __attribute__((ext_vector_type(8)));
typedef float    f32x4 __attribute__((ext_vector_type(4)));

static_assert(sizeof(f16x8) == 16, "f16x8 must be 16B");

#define B_  16
#define C_  256
#define CH_ 128
#define N_  2048

DI f32x4 fzero(){ f32x4 z = {0.f,0.f,0.f,0.f}; return z; }
DI f16x8 ldg8(const f16_t* p){ return *(const f16x8*)p; }
DI f32x4 mfma16(f16x8 a, f16x8 b, f32x4 c){
  return __builtin_amdgcn_mfma_f32_16x16x32_f16(a, b, c, 0, 0, 0);
}
DI void split2(float v, f16_t& hi, f16_t& lo){
  hi = (f16_t)v; lo = (f16_t)(v - (float)hi);
}

// ---------------------------------------------------------------------------
// Weight fp32 -> fp16 hi/lo split pack. Per layer: WqS[128][512] WkS[128][512]
// WvS[256][512] WtS[256][512] (cols 0..255 = hi, 256..511 = lo).
__global__ void k_wconv(const float* q1,const float* k1,const float* v1,const float* t1,
                        const float* q2,const float* k2,const float* v2,const float* t2,
                        f16_t* out){
  int i = blockIdx.x*256 + threadIdx.x;            // 0..393215
  int l = (i >= 196608) ? 1 : 0;
  int r = i - l*196608;
  const float* s; long dbase;
  if(r < 32768){ s = l? q2:q1; dbase = 0; }
  else if(r < 65536){ r -= 32768; s = l? k2:k1; dbase = 65536; }
  else if(r < 131072){ r -= 65536; s = l? v2:v1; dbase = 131072; }
  else { r -= 131072; s = l? t2:t1; dbase = 262144; }
  int o = r >> 8, c = r & 255;
  float v = s[o*256 + c];
  f16_t hi, lo; split2(v, hi, lo);
  f16_t* d = out + (long)l*393216 + dbase + (long)o*512;
  d[c] = hi; d[c+256] = lo;
}

// ---------------------------------------------------------------------------
// Transpose+split: XtS[b][n][512] = {hi(x[b][:,n]), lo}. grid (B, N/32, C/32)
__global__ void k_transpose(const float* __restrict__ X, long bstride,
                            f16_t* __restrict__ XtS){
  int b = blockIdx.x, n0 = blockIdx.y*32, c0 = blockIdx.z*32;
  __shared__ float tl[32][33];
  int t = threadIdx.x;
  int nn = t & 31, r = t >> 5;                      // r in 0..7
  const float* src = X + (long)b*bstride;
  #pragma unroll
  for(int i=0;i<4;i++){
    int cc = r + i*8;
    tl[nn][cc] = src[(long)(c0+cc)*N_ + n0 + nn];
  }
  __syncthreads();
  f16_t* dst = XtS + ((long)b*N_ + n0)*512 + c0;
  #pragma unroll
  for(int i=0;i<4;i++){
    int n2 = r + i*8;
    f16_t hi, lo; split2(tl[n2][nn], hi, lo);
    dst[(long)n2*512 + nn]       = hi;
    dst[(long)n2*512 + nn + 256] = lo;
  }
}

// ---------------------------------------------------------------------------
// 3-term split GEMM: out[row][col] = sum_k (Ah+Al)[row][k]*(Bh+Bl)[col][k]
// (drops Al*Bl). A,B rows are 512-wide hi|lo, K=256. 64x64 tile, 4 waves.
template<int SPLIT_OUT, int BIAS>
__global__ __launch_bounds__(256) void k_gemm3(
    const f16_t* __restrict__ A, long sA,
    const f16_t* __restrict__ Bt, long sB,
    f16_t* __restrict__ out, int ldo, long sO,
    const float* __restrict__ bias)
{
  int b = blockIdx.x;
  int m0 = blockIdx.y*64, n0 = blockIdx.z*64;
  int t = threadIdx.x, w = t>>6, l = t&63, lr = l&15, lg = l>>4;
  const f16_t* Ab = A + (long)b*sA + (long)(m0 + w*16 + lr)*512;
  const f16_t* Bb = Bt + (long)b*sB;
  f32x4 acc[4];
  #pragma unroll
  for(int i=0;i<4;i++) acc[i] = fzero();
  for(int k=0;k<256;k+=32){
    f16x8 ah = ldg8(Ab + k + lg*8);
    f16x8 al = ldg8(Ab + 256 + k + lg*8);
    #pragma unroll
    for(int ns=0;ns<4;ns++){
      const f16_t* brow = Bb + (long)(n0 + ns*16 + lr)*512;
      f16x8 bh = ldg8(brow + k + lg*8);
      f16x8 bl = ldg8(brow + 256 + k + lg*8);
      acc[ns] = mfma16(ah, bh, acc[ns]);
      acc[ns] = mfma16(ah, bl, acc[ns]);
      acc[ns] = mfma16(al, bh, acc[ns]);
    }
  }
  f16_t* ob = out + (long)b*sO;
  #pragma unroll
  for(int ns=0;ns<4;ns++){
    #pragma unroll
    for(int j=0;j<4;j++){
      int row = m0 + w*16 + lg*4 + j;
      int col = n0 + ns*16 + lr;
      float v = acc[ns][j];
      if(BIAS) v += bias[row];
      if(SPLIT_OUT){
        f16_t hi, lo; split2(v, hi, lo);
        ob[(long)row*ldo + col]       = hi;
        ob[(long)row*ldo + col + 128] = lo;
      } else {
        ob[(long)row*ldo + col] = (f16_t)v;
      }
    }
  }
}

// ---------------------------------------------------------------------------
// Pass 1: rowoff[b][n] = rowmax + ln(sum exp). 3-term split energies.
__global__ __launch_bounds__(256) void k_rowstats(
    const f16_t* __restrict__ xqS, const f16_t* __restrict__ xkS,
    float* __restrict__ rowoff)
{
  const int b = blockIdx.x, n0 = blockIdx.y*64;
  const int t = threadIdx.x, w = t>>6, l = t&63, lr = l&15, lg = l>>4;
  const f16_t* qp = xqS + ((long)b*N_ + n0 + w*16 + lr)*256;
  f16x8 bqh[4], bql[4];
  #pragma unroll
  for(int k=0;k<4;k++){
    bqh[k] = ldg8(qp + k*32 + lg*8);
    bql[k] = ldg8(qp + 128 + k*32 + lg*8);
  }
  const f16_t* kb = xkS + (long)b*N_*256;
  float rmax = -3e38f, rsum = 0.f;
  for(int m0=0;m0<N_;m0+=64){
    #pragma unroll
    for(int s=0;s<4;s++){
      const f16_t* kr = kb + (long)(m0 + s*16 + lr)*256;
      f16x8 ah[4], al_[4];
      #pragma unroll
      for(int k=0;k<4;k++){
        ah[k]  = ldg8(kr + k*32 + lg*8);
        al_[k] = ldg8(kr + 128 + k*32 + lg*8);
      }
      f32x4 acc = fzero();
      #pragma unroll
      for(int k=0;k<4;k++) acc = mfma16(ah[k],  bqh[k], acc);
      #pragma unroll
      for(int k=0;k<4;k++) acc = mfma16(ah[k],  bql[k], acc);
      #pragma unroll
      for(int k=0;k<4;k++) acc = mfma16(al_[k], bqh[k], acc);
      float vm = fmaxf(fmaxf(acc[0],acc[1]), fmaxf(acc[2],acc[3]));
      float nm = fmaxf(rmax, vm);
      rsum = rsum*__expf(rmax-nm)
           + __expf(acc[0]-nm)+__expf(acc[1]-nm)+__expf(acc[2]-nm)+__expf(acc[3]-nm);
      rmax = nm;
    }
  }
  #pragma unroll
  for(int off=16; off<64; off<<=1){
    float om = __shfl_xor(rmax, off, 64);
    float os = __shfl_xor(rsum, off, 64);
    float nm = fmaxf(rmax, om);
    rsum = rsum*__expf(rmax-nm) + os*__expf(om-nm);
    rmax = nm;
  }
  if(lg==0) rowoff[(long)b*N_ + n0 + w*16 + lr] = rmax + __logf(rsum);
}

// ---------------------------------------------------------------------------
// Pass 2 (flash-col): g = e - ro[n]; online per-COLUMN max cm[m]; P=exp(g-cm)
// fp16; S += P (rounded); Y = Y*exp(old-new) + xv @ P;
// h0 = X - Y/(1e-9*exp(-cm) + S). grid (B, N/64 m-tiles).
__global__ __launch_bounds__(256) void k_apply(
    const f16_t* __restrict__ xqS, const f16_t* __restrict__ xkS,
    const f16_t* __restrict__ xv, const float* __restrict__ rowoff,
    const float* __restrict__ X, long xbstride, f16_t* __restrict__ h0T)
{
  const int b = blockIdx.x, m0 = blockIdx.y*64;
  const int t = threadIdx.x, w = t>>6, l = t&63, lr = l&15, lg = l>>4;
  __shared__ __align__(16) char smem[33280];
  f16_t* Ps = (f16_t*)smem;                   // swizzled [64][32] fp16 (4KB)
  f16_t* H  = (f16_t*)smem;                   // swizzled [64][256] fp16 (epilogue)
  float* Fs   = (float*)(smem + 32768);       // [64] rescale factors (loop)
  float* csum = (float*)(smem + 32768);       // [64] (end, reuses Fs)
  float* cmx  = (float*)(smem + 33024);       // [64] final colmax (end)

  const f16_t* akp = xkS + ((long)b*N_ + m0 + w*16 + lr)*256;
  f16x8 akh[4], akl[4];
  #pragma unroll
  for(int k=0;k<4;k++){
    akh[k] = ldg8(akp + k*32 + lg*8);
    akl[k] = ldg8(akp + 128 + k*32 + lg*8);
  }

  const f16_t* xqb = xqS + (long)b*N_*256;
  const f16_t* xvb = xv + (long)b*C_*N_ + (long)(w*64 + lr)*N_;
  const float*  rob = rowoff + (long)b*N_;

  f32x4 y[4][4];
  #pragma unroll
  for(int i=0;i<4;i++){
    #pragma unroll
    for(int j=0;j<4;j++) y[i][j] = fzero();
  }
  float cs[4] = {0.f,0.f,0.f,0.f};
  float cm[4] = {-3e38f,-3e38f,-3e38f,-3e38f};

  for(int n0=0; n0<N_; n0+=32){
    // energies -> g = e - ro for both 16-n halves
    float g[2][4];
    #pragma unroll
    for(int s2=0;s2<2;s2++){
      const f16_t* qr = xqb + (long)(n0 + s2*16 + lr)*256;
      f16x8 qh[4], ql[4];
      #pragma unroll
      for(int k=0;k<4;k++){
        qh[k] = ldg8(qr + k*32 + lg*8);
        ql[k] = ldg8(qr + 128 + k*32 + lg*8);
      }
      f32x4 e = fzero();
      #pragma unroll
      for(int k=0;k<4;k++) e = mfma16(akh[k], qh[k], e);
      #pragma unroll
      for(int k=0;k<4;k++) e = mfma16(akl[k], qh[k], e);
      #pragma unroll
      for(int k=0;k<4;k++) e = mfma16(akh[k], ql[k], e);
      float ro = rob[n0 + s2*16 + lr];
      #pragma unroll
      for(int j=0;j<4;j++) g[s2][j] = e[j] - ro;
    }
    // online column-max update; column = m0 + w*16 + lg*4 + j (same for all lr)
    float f[4];
    #pragma unroll
    for(int j=0;j<4;j++){
      float v = fmaxf(g[0][j], g[1][j]);
      #pragma unroll
      for(int off=1; off<16; off<<=1) v = fmaxf(v, __shfl_xor(v, off, 64));
      float nm = fmaxf(cm[j], v);
      f[j] = __expf(cm[j] - nm);
      cm[j] = nm;
      cs[j] *= f[j];
    }
    // P tile (fp16) + colsum from the SAME rounded values
    #pragma unroll
    for(int s2=0;s2<2;s2++){
      #pragma unroll
      for(int j=0;j<4;j++){
        float p = __expf(g[s2][j] - cm[j]);
        f16_t pb = (f16_t)p;
        cs[j] += (float)pb;
        int m = w*16 + lg*4 + j, n = s2*16 + lr;  // Ps[m][n] swizzled (64B rows)
        *(f16_t*)((char*)Ps + m*64 + ((((n>>3) ^ (m&3))<<4) | ((n&7)<<1))) = pb;
      }
    }
    if(lr==0){
      #pragma unroll
      for(int j=0;j<4;j++) Fs[w*16 + lg*4 + j] = f[j];
    }
    __syncthreads();
    // rescale Y by per-column factors, then accumulate PV
    float fac[4];
    #pragma unroll
    for(int ms=0;ms<4;ms++) fac[ms] = Fs[ms*16 + lr];
    #pragma unroll
    for(int cc=0;cc<4;cc++){
      #pragma unroll
      for(int ms=0;ms<4;ms++){
        #pragma unroll
        for(int j2=0;j2<4;j2++) y[cc][ms][j2] *= fac[ms];
      }
    }
    f16x8 av[4];
    #pragma unroll
    for(int cc=0;cc<4;cc++) av[cc] = ldg8(xvb + (long)cc*16*N_ + n0 + lg*8);
    #pragma unroll
    for(int ms=0;ms<4;ms++){
      int m = ms*16 + lr;
      f16x8 bp = *(const f16x8*)((const char*)Ps + m*64 + (((lg ^ (m&3))<<4)));
      #pragma unroll
      for(int cc=0;cc<4;cc++) y[cc][ms] = mfma16(av[cc], bp, y[cc][ms]);
    }
    __syncthreads();
  }

  // reduce colsum partials over the 16 n-lanes
  #pragma unroll
  for(int off=1; off<16; off<<=1){
    #pragma unroll
    for(int j=0;j<4;j++) cs[j] += __shfl_xor(cs[j], off, 64);
  }
  if(lr==0){
    #pragma unroll
    for(int j=0;j<4;j++){
      csum[w*16 + lg*4 + j] = cs[j];
      cmx [w*16 + lg*4 + j] = cm[j];
    }
  }
  __syncthreads();
  float inv[4];
  #pragma unroll
  for(int ms=0;ms<4;ms++){
    float S = csum[ms*16 + lr], CM = cmx[ms*16 + lr];
    inv[ms] = 1.f/(1e-9f*__expf(-CM) + S);
  }
  const float* Xb = X + (long)b*xbstride;
  #pragma unroll
  for(int cc=0;cc<4;cc++){
    #pragma unroll
    for(int ms=0;ms<4;ms++){
      #pragma unroll
      for(int j=0;j<4;j++){
        int c  = w*64 + cc*16 + lg*4 + j;
        int ml = ms*16 + lr;
        float h0v = Xb[(long)c*N_ + m0 + ml] - y[cc][ms][j]*inv[ms];
        *(f16_t*)((char*)H + ml*512 + ((((c>>3) ^ (ml&7))<<4) | ((c&7)<<1))) = (f16_t)h0v;
      }
    }
  }
  __syncthreads();
  {
    uint4* dst = (uint4*)(h0T + ((long)b*N_ + m0)*C_);
    const uint4* src = (const uint4*)H;
    for(int i=t;i<2048;i+=256){
      int row = i>>5, slot = i&31;
      dst[i] = src[(i & ~31) | (slot ^ (row&7))];
    }
  }
}

// ---------------------------------------------------------------------------
// h1[b][o][m] = Wt @ h0 + bt (2-term: Wt hi+lo) + BN partial sums (atomics).
__global__ __launch_bounds__(256) void k_wt_bn(
    const f16_t* __restrict__ WtS, const f16_t* __restrict__ h0T,
    const float* __restrict__ bt,
    float* __restrict__ h1, float* __restrict__ bnacc)
{
  int b = blockIdx.x, o0 = blockIdx.y*64, m0 = blockIdx.z*64;
  int t=threadIdx.x, w=t>>6, l=t&63, lr=l&15, lg=l>>4;
  const f16_t* Arow = WtS + (long)(o0 + w*16 + lr)*512;
  const f16_t* Bb = h0T + (long)b*N_*C_;
  f32x4 acc[4];
  #pragma unroll
  for(int i=0;i<4;i++) acc[i] = fzero();
  for(int k=0;k<C_;k+=32){
    f16x8 afh = ldg8(Arow + k + lg*8);
    f16x8 afl = ldg8(Arow + 256 + k + lg*8);
    #pragma unroll
    for(int ms=0;ms<4;ms++){
      f16x8 bf_ = ldg8(Bb + (long)(m0 + ms*16 + lr)*C_ + k + lg*8);
      acc[ms] = mfma16(afh, bf_, acc[ms]);
      acc[ms] = mfma16(afl, bf_, acc[ms]);
    }
  }
  float s1[4]={0.f,0.f,0.f,0.f}, s2v[4]={0.f,0.f,0.f,0.f};
  float* h1b = h1 + (long)b*C_*N_;
  #pragma unroll
  for(int j=0;j<4;j++){
    int o = o0 + w*16 + lg*4 + j;
    float bias = bt[o];
    #pragma unroll
    for(int ms=0;ms<4;ms++){
      float v = acc[ms][j] + bias;
      h1b[(long)o*N_ + m0 + ms*16 + lr] = v;
      s1[j] += v; s2v[j] += v*v;
    }
  }
  #pragma unroll
  for(int off=1; off<16; off<<=1){
    #pragma unroll
    for(int j=0;j<4;j++){ s1[j]+=__shfl_xor(s1[j],off,64); s2v[j]+=__shfl_xor(s2v[j],off,64); }
  }
  if(lr==0){
    #pragma unroll
    for(int j=0;j<4;j++){
      int o = o0 + w*16 + lg*4 + j;
      atomicAdd(&bnacc[o], s1[j]);
      atomicAdd(&bnacc[256+o], s2v[j]);
    }
  }
}

// BN finalize -> scale/shift
__global__ void k_bnfin(const float* __restrict__ bnacc, const float* __restrict__ gamma,
                        const float* __restrict__ beta, float* __restrict__ scsh){
  int o = threadIdx.x;
  float mean = bnacc[o] * (1.f/32768.f);
  float var  = bnacc[256+o] * (1.f/32768.f) - mean*mean;
  float sc = gamma[o] * rsqrtf(var + 1e-5f);
  scsh[o] = sc;
  scsh[256+o] = beta[o] - mean*sc;
}

// out = X + relu(h1*sc + sh); writes one 256-channel half of d_out.
__global__ void k_out(const float* __restrict__ h1, const float* __restrict__ X, long xbstride,
                      const float* __restrict__ scsh, float* __restrict__ out, long ocoff){
  long i = (long)blockIdx.x*256 + threadIdx.x;
  long e = i*4;
  int b = (int)(e >> 19);
  int rem = (int)(e & 524287);                  // c*2048 + m
  int c = rem >> 11;
  float4 hv = *(const float4*)(h1 + e);
  float4 xr = *(const float4*)(X + (long)b*xbstride + rem);
  float sc = scsh[c], sh = scsh[256+c];
  float4 o;
  o.x = xr.x + fmaxf(fmaf(hv.x, sc, sh), 0.f);
  o.y = xr.y + fmaxf(fmaf(hv.y, sc, sh), 0.f);
  o.z = xr.z + fmaxf(fmaf(hv.z, sc, sh), 0.f);
  o.w = xr.w + fmaxf(fmaf(hv.w, sc, sh), 0.f);
  *(float4*)(out + (long)b*(512L*N_) + ocoff + rem) = o;
}

// ---------------------------------------------------------------------------
extern "C" void kernel_launch(void* const* d_in, const int* in_sizes, int n_in,
                              void* d_out, int out_size, void* d_ws, size_t ws_size,
                              hipStream_t stream){
  (void)in_sizes; (void)n_in; (void)out_size; (void)ws_size;
  const float* x = (const float*)d_in[0];
  const float *Wf[2][4], *bv[2], *bt[2], *gm[2], *bb[2];
  for(int l=0;l<2;l++){
    int base = 1 + l*8;
    Wf[l][0]=(const float*)d_in[base+0];  // Wq
    Wf[l][1]=(const float*)d_in[base+1];  // Wk
    Wf[l][2]=(const float*)d_in[base+2];  // Wv
    bv[l]   =(const float*)d_in[base+3];
    Wf[l][3]=(const float*)d_in[base+4];  // Wt
    bt[l]   =(const float*)d_in[base+5];
    gm[l]   =(const float*)d_in[base+6];
    bb[l]   =(const float*)d_in[base+7];
  }
  char* ws = (char*)d_ws;
  size_t off = 0;
  auto alloc = [&](size_t bytes){ size_t o = off; off += (bytes + 255) & ~(size_t)255; return o; };
  size_t oXt = alloc((size_t)B_*N_*512*2);     // fp16 split x^T
  size_t oXq = alloc((size_t)B_*N_*256*2);     // fp16 split q [n][256]
  size_t oXk = alloc((size_t)B_*N_*256*2);     // fp16 split k [m][256]
  size_t oXv = alloc((size_t)B_*C_*N_*2);      // fp16 v [c][n]
  size_t oH0 = alloc((size_t)B_*N_*C_*2);      // fp16 h0^T [m][c]
  size_t oRo = alloc((size_t)B_*N_*4);         // f32 rowoff
  size_t oBn = alloc(2*512*4);                 // BN accum per layer
  size_t oSc = alloc(2*512*4);                 // BN scale/shift per layer
  size_t oW  = alloc((size_t)786432*2);        // fp16 split weights

  hipMemsetAsync(ws + oBn, 0, 2*512*4, stream);
  k_wconv<<<1536,256,0,stream>>>(Wf[0][0],Wf[0][1],Wf[0][2],Wf[0][3],
                                 Wf[1][0],Wf[1][1],Wf[1][2],Wf[1][3],
                                 (f16_t*)(ws+oW));
  float* dout = (float*)d_out;
  float* H1 = (float*)(ws + oXq);              // aliases Xq+Xk (dead when used)
  for(int l=0;l<2;l++){
    const float* Xl = l ? dout : x;
    long xbs = l ? 512L*N_ : 256L*N_;
    const f16_t* WqS = (const f16_t*)(ws+oW) + (size_t)l*393216;
    const f16_t* WkS = WqS + 65536;
    const f16_t* WvS = WqS + 131072;
    const f16_t* WtS = WqS + 262144;
    f16_t* XtS = (f16_t*)(ws+oXt);
    f16_t* Xq  = (f16_t*)(ws+oXq);
    f16_t* Xk  = (f16_t*)(ws+oXk);
    f16_t* Xv  = (f16_t*)(ws+oXv);
    f16_t* H0  = (f16_t*)(ws+oH0);
    float* Ro  = (float*)(ws+oRo);
    float* Bn  = (float*)(ws+oBn) + l*512;
    float* Sc  = (float*)(ws+oSc) + l*512;

    k_transpose<<<dim3(B_, N_/32, C_/32),256,0,stream>>>(Xl, xbs, XtS);
    k_gemm3<1,0><<<dim3(B_,32,2),256,0,stream>>>(XtS, (long)N_*512, WqS, 0L,
                                                 Xq, 256, (long)N_*256, nullptr);
    k_gemm3<1,0><<<dim3(B_,32,2),256,0,stream>>>(XtS, (long)N_*512, WkS, 0L,
                                                 Xk, 256, (long)N_*256, nullptr);
    k_gemm3<0,1><<<dim3(B_,4,32),256,0,stream>>>(WvS, 0L, XtS, (long)N_*512,
                                                 Xv, N_, (long)C_*N_, bv[l]);
    k_rowstats<<<dim3(B_, N_/64),256,0,stream>>>(Xq, Xk, Ro);
    k_apply<<<dim3(B_, N_/64),256,0,stream>>>(Xq, Xk, Xv, Ro, Xl, xbs, H0);
    k_wt_bn<<<dim3(B_,4,32),256,0,stream>>>(WtS, H0, bt[l], H1, Bn);
    k_bnfin<<<1,256,0,stream>>>(Bn, gm[l], bb[l], Sc);
    k_out<<<8192,256,0,stream>>>(H1, Xl, xbs, Sc, dout, (long)l*C_*N_);
  }
}